// Round 7
// baseline (104.801 us; speedup 1.0000x reference)
//
#include <hip/hip_runtime.h>

// SparsePropMaxPool closed form (verified rounds 1-6, absmax=0):
//   ori_map_h[b,h,s,e] = max(x[b,h,s..e]) if (s, d=e-s) in SET else 0
//   SET: d in [0,15] any s | d odd in [17,31], s even | d%4==3 in [35,63], s%4==0
//   props_h[b,p,h] = max(x[b,h, s_p .. s_p+d_p])  (153 constant ranges)
//   mask[b,0,s,e] = 1 at SET positions
// Out layout: props (64*153*512) | map (64*512*64*64) | mask (64*64*64)
//
// R6 structure (best, 101.5us): heterogeneous grid, one dispatch.
//   blocks 0..63: props+mask only (hidden under map BW)
//   blocks 64..2111: 16-row map tile, float4 stores, no post-store barrier
// R7 single-variable A/B: map stores PLAIN (was nontemporal). Fill kernel
// (plain stores) sustains 6.7-6.9 TB/s on this buffer; nt bypasses the L2
// write-back batching that may be what gets it there.

#define B_ 64
#define H_ 512
#define N_ 64
#define NPROP 153

typedef float f4 __attribute__((ext_vector_type(4)));

__device__ __forceinline__ bool in_set(int s, int d) {
    if (d < 0) return false;
    if (d <= 15) return true;
    if (d <= 31) return (d & 1) && ((s & 1) == 0);        // d=17,19..31 odd, s even
    return (d >= 35) && ((d & 3) == 3) && ((s & 3) == 0); // d=35,39..63, s%4==0
}

__global__ __launch_bounds__(256) void fused_kernel(const float* __restrict__ x,
                                                    float* __restrict__ out_props,
                                                    float* __restrict__ out_map,
                                                    float* __restrict__ out_mask) {
    const int tid = threadIdx.x;    // 0..255
    const int bid = blockIdx.x;     // 0..2111

    __shared__ __align__(16) float xs[16][72];   // map path only (4.6KB)

    if (bid < B_) {
        // ---------------- props + mask block: one batch b ----------------
        const int b = bid;

        // mask: 64x64 = 1024 f4, 4 per thread
        f4* mk = reinterpret_cast<f4*>(out_mask + (size_t)b * (N_ * N_));
        #pragma unroll
        for (int i = 0; i < 4; ++i) {
            const int idx = tid + 256 * i;   // f4 index; s = idx>>4, c = idx&15
            const int s = idx >> 4, c = idx & 15;
            f4 w;
            w.x = in_set(s, 4 * c + 0 - s) ? 1.f : 0.f;
            w.y = in_set(s, 4 * c + 1 - s) ? 1.f : 0.f;
            w.z = in_set(s, 4 * c + 2 - s) ? 1.f : 0.f;
            w.w = in_set(s, 4 * c + 3 - s) ? 1.f : 0.f;
            __builtin_nontemporal_store(w, &mk[idx]);
        }

        // props: 512 h rows, 2 per thread, sequential (keep VGPR low)
        #pragma unroll 1
        for (int half = 0; half < 2; ++half) {
            const int h = tid + 256 * half;
            const f4* xr = reinterpret_cast<const f4*>(x + ((size_t)b * H_ + h) * N_);
            float r[64];
            #pragma unroll
            for (int k = 0; k < 16; ++k) {
                f4 v = xr[k];
                r[4*k+0] = v.x; r[4*k+1] = v.y; r[4*k+2] = v.z; r[4*k+3] = v.w;
            }
            float a[63];
            #pragma unroll
            for (int i = 0; i < 63; ++i) a[i] = fmaxf(r[i], r[i+1]);
            float m4[61];
            #pragma unroll
            for (int i = 0; i < 61; ++i) m4[i] = fmaxf(a[i], a[i+2]);
            float T3[57];                    // T3[i] = max(x[i..i+7])
            #pragma unroll
            for (int i = 0; i < 57; ++i) T3[i] = fmaxf(m4[i], m4[i+4]);

            float* po = out_props + (size_t)b * NPROP * H_ + h;
            int p = 0;
            #pragma unroll
            for (int s = 0; s < 57; ++s)              // d=7
                __builtin_nontemporal_store(T3[s], &po[(size_t)(p++) * H_]);
            #pragma unroll
            for (int s = 0; s < 49; ++s)              // d=15
                __builtin_nontemporal_store(fmaxf(T3[s], T3[s + 8]),
                                            &po[(size_t)(p++) * H_]);
            #pragma unroll
            for (int s = 0; s <= 40; s += 2)          // d=23
                __builtin_nontemporal_store(fmaxf(fmaxf(T3[s], T3[s + 8]), T3[s + 16]),
                                            &po[(size_t)(p++) * H_]);
            #pragma unroll
            for (int s = 0; s <= 32; s += 2)          // d=31
                __builtin_nontemporal_store(
                    fmaxf(fmaxf(T3[s], T3[s + 8]), fmaxf(T3[s + 16], T3[s + 24])),
                    &po[(size_t)(p++) * H_]);
            #pragma unroll
            for (int s = 0; s <= 16; s += 4) {        // d=47
                float m = T3[s];
                #pragma unroll
                for (int j = 8; j <= 40; j += 8) m = fmaxf(m, T3[s + j]);
                __builtin_nontemporal_store(m, &po[(size_t)(p++) * H_]);
            }
            #pragma unroll
            for (int s = 0; s <= 8; s += 4) {         // d=55
                float m = T3[s];
                #pragma unroll
                for (int j = 8; j <= 48; j += 8) m = fmaxf(m, T3[s + j]);
                __builtin_nontemporal_store(m, &po[(size_t)(p++) * H_]);
            }
            {                                         // d=63
                float m = T3[0];
                #pragma unroll
                for (int j = 8; j <= 56; j += 8) m = fmaxf(m, T3[j]);
                __builtin_nontemporal_store(m, &po[(size_t)p * H_]);
            }
        }
        return;
    }

    // ---------------- map block: 16 bh-rows, PLAIN float4 stores ----------------
    const int mb = bid - B_;            // 0..2047
    const int g  = tid >> 4;            // row within block 0..15
    const int t  = tid & 15;            // float4 column 0..15
    const size_t bh = (size_t)mb * 16 + g;

    f4 xv = reinterpret_cast<const f4*>(x)[mb * 256 + tid];
    *reinterpret_cast<f4*>(&xs[g][4 * t]) = xv;
    __syncthreads();

    f4* mrow = reinterpret_cast<f4*>(out_map + bh * (size_t)(N_ * N_));
    const int e0 = 4 * t;
    float vx = 0.f, vy = 0.f, vz = 0.f, vw = 0.f;
    #pragma unroll
    for (int s = N_ - 1; s >= 0; --s) {   // v_j = max(x[s..e_j]), reset at s==e_j
        const float mv = xs[g][s];
        vx = (s == e0 + 0) ? mv : fmaxf(vx, mv);
        vy = (s == e0 + 1) ? mv : fmaxf(vy, mv);
        vz = (s == e0 + 2) ? mv : fmaxf(vz, mv);
        vw = (s == e0 + 3) ? mv : fmaxf(vw, mv);
        f4 w;
        w.x = in_set(s, e0 + 0 - s) ? vx : 0.f;   // s compile-time -> t-compares
        w.y = in_set(s, e0 + 1 - s) ? vy : 0.f;
        w.z = in_set(s, e0 + 2 - s) ? vz : 0.f;
        w.w = in_set(s, e0 + 3 - s) ? vw : 0.f;
        mrow[s * 16 + t] = w;              // plain store (A/B vs R6's nt)
    }
}

extern "C" void kernel_launch(void* const* d_in, const int* in_sizes, int n_in,
                              void* d_out, int out_size, void* d_ws, size_t ws_size,
                              hipStream_t stream) {
    const float* x = (const float*)d_in[0];   // (64, 512, 64) f32
    float* out       = (float*)d_out;
    float* out_props = out;                                   // 5,013,504
    float* out_map   = out + (size_t)B_ * NPROP * H_;         // 134,217,728
    float* out_mask  = out_map + (size_t)B_ * H_ * N_ * N_;   // 262,144

    fused_kernel<<<dim3(B_ + B_ * H_ / 16), dim3(256), 0, stream>>>(
        x, out_props, out_map, out_mask);
}